// Round 15
// baseline (66.422 us; speedup 1.0000x reference)
//
#include <hip/hip_runtime.h>

#define NB 4
#define SEQ 4096
#define EMB 768
#define AD 64
#define BS (NB*SEQ)
#define CHK 16   // kv tiles (of 64) per chunk

typedef short short8 __attribute__((ext_vector_type(8)));
typedef float f32x4 __attribute__((ext_vector_type(4)));
typedef int   i32x2 __attribute__((ext_vector_type(2)));
typedef unsigned short u16;

__device__ __forceinline__ u16 f2bf(float f) {
  union { float f; unsigned u; } v; v.f = f;
  unsigned u = v.u;
  unsigned r = (u + 0x7FFFu + ((u >> 16) & 1u)) >> 16;  // RNE
  return (u16)r;
}

__device__ __forceinline__ unsigned cvt_pk_bf16(float lo, float hi) {
  unsigned r;
  asm("v_cvt_pk_bf16_f32 %0, %1, %2" : "=v"(r) : "v"(lo), "v"(hi));
  return r;
}

__device__ __forceinline__ f32x4 mfma16(short8 a, short8 b, f32x4 c) {
  return __builtin_amdgcn_mfma_f32_16x16x32_bf16(a, b, c, 0, 0, 0);
}

// async global->LDS, 16B per lane; LDS dest = uniform base + lane*16
__device__ __forceinline__ void gload16(const u16* g, u16* l) {
  __builtin_amdgcn_global_load_lds(
      (const __attribute__((address_space(1))) unsigned*)g,
      (__attribute__((address_space(3))) unsigned*)l, 16, 0, 0);
}

__device__ __forceinline__ float xor16_max(float x) {
#if __has_builtin(__builtin_amdgcn_permlane16_swap)
  i32x2 r = __builtin_amdgcn_permlane16_swap(__float_as_int(x), __float_as_int(x), false, false);
  return fmaxf(__int_as_float(r[0]), __int_as_float(r[1]));
#else
  return fmaxf(x, __shfl_xor(x, 16));
#endif
}
__device__ __forceinline__ float xor16_sum(float x) {
#if __has_builtin(__builtin_amdgcn_permlane16_swap)
  i32x2 r = __builtin_amdgcn_permlane16_swap(__float_as_int(x), __float_as_int(x), false, false);
  return __int_as_float(r[0]) + __int_as_float(r[1]);
#else
  return x + __shfl_xor(x, 16);
#endif
}
__device__ __forceinline__ float xor32_max(float x) {
#if __has_builtin(__builtin_amdgcn_permlane32_swap)
  i32x2 r = __builtin_amdgcn_permlane32_swap(__float_as_int(x), __float_as_int(x), false, false);
  return fmaxf(__int_as_float(r[0]), __int_as_float(r[1]));
#else
  return fmaxf(x, __shfl_xor(x, 32));
#endif
}
__device__ __forceinline__ float xor32_sum(float x) {
#if __has_builtin(__builtin_amdgcn_permlane32_swap)
  i32x2 r = __builtin_amdgcn_permlane32_swap(__float_as_int(x), __float_as_int(x), false, false);
  return __int_as_float(r[0]) + __int_as_float(r[1]);
#else
  return x + __shfl_xor(x, 32);
#endif
}

// ---------------- Kernel 0: weight transpose + bf16 cast (PASSING) ----------
// Wt[(m*64 + col)*768 + e] = W_m[e*64 + col]
__global__ void wt_kernel(const float* __restrict__ Wq, const float* __restrict__ Wk,
                          const float* __restrict__ Wv, u16* __restrict__ Wt) {
  int idx = blockIdx.x * 256 + threadIdx.x;
  if (idx >= 3 * AD * EMB) return;
  int m   = idx / (AD * EMB);
  int rem = idx - m * (AD * EMB);
  int col = rem / EMB;
  int e   = rem - col * EMB;
  const float* W = (m == 0) ? Wq : (m == 1) ? Wk : Wv;
  Wt[idx] = f2bf(W[e * AD + col]);
}

// ---------------- Kernel 1: QKV projection, LDS-staged GEMM v6 --------------
// 4-BLOCKS/CU version: block = 16 rows x 256 threads (4 waves), grid 1024.
// Each wave owns 3 of the 12 col-fragments (fg = w*3+fi) over the FULL K.
// LDS ~30 KB -> 5 blocks/CU by LDS; grid gives 4/CU = 16 waves/CU of
// latency hiding. Load/swizzle formulas and per-output accumulation order
// IDENTICAL to passing R14 (geometry-only re-mapping).
__global__ __launch_bounds__(256, 4) void proj_kernel(const float* __restrict__ emb,
                                                      const u16* __restrict__ Wt,
                                                      u16* __restrict__ Q, u16* __restrict__ K,
                                                      u16* __restrict__ Vt) {
  const int w = threadIdx.x >> 6;       // wave 0..3 = col-quarter (3 fragments)
  const int lane = threadIdx.x & 63;
  const int g = lane >> 4, c = lane & 15;
  const int rbase = blockIdx.x * 16;

  __shared__ __align__(16) char ebuf[2][2048];    // [16 rows][128B fp32], key row&7
  __shared__ __align__(16) char wbuf[2][12288];   // [192 cols][64B bf16], key (col&3)^((col>>2)&3)
  __shared__ u16 t[16][65];                       // V transpose staging

  const int r8 = lane >> 3, j8 = lane & 7;        // emb staging decomposition
  const int c4 = lane >> 2, j4 = lane & 3;        // wt staging decomposition

  f32x4 acc[3];
#pragma unroll
  for (int fi = 0; fi < 3; ++fi)
#pragma unroll
    for (int r = 0; r < 4; ++r) acc[fi][r] = 0.f;

  // staging per k-step: each wave 3 Wt col-groups (w, 4+w, 8+w); waves 0-1
  // additionally stage the 16 emb rows (8 each).
#define PSTAGE(bufi, kt) do {                                                  \
    { const int col = w * 16 + c4;                                             \
      const int kc = (col & 3) ^ ((col >> 2) & 3);                             \
      gload16(Wt + (size_t)col * EMB + (kt) * 32 + ((j4 ^ kc) << 3),           \
              (u16*)(wbuf[bufi] + w * 1024)); }                                \
    { const int col = (4 + w) * 16 + c4;                                       \
      const int kc = (col & 3) ^ ((col >> 2) & 3);                             \
      gload16(Wt + (size_t)col * EMB + (kt) * 32 + ((j4 ^ kc) << 3),           \
              (u16*)(wbuf[bufi] + (4 + w) * 1024)); }                          \
    { const int col = (8 + w) * 16 + c4;                                       \
      const int kc = (col & 3) ^ ((col >> 2) & 3);                             \
      gload16(Wt + (size_t)col * EMB + (kt) * 32 + ((j4 ^ kc) << 3),           \
              (u16*)(wbuf[bufi] + (8 + w) * 1024)); }                          \
    if (w < 2) {                                                               \
      gload16((const u16*)(emb + (size_t)(rbase + w * 8 + r8) * EMB            \
                           + (kt) * 32 + ((j8 ^ r8) << 2)),                    \
              (u16*)(ebuf[bufi] + w * 1024));                                  \
    }                                                                          \
  } while (0)

  PSTAGE(0, 0);
  __syncthreads();

  int cur = 0;
  for (int kt = 0; kt < 24; ++kt) {
    if (kt + 1 < 24) PSTAGE(cur ^ 1, kt + 1);

    // A fragment: row c, 8 floats (k = g*8..g*8+8), swizzled slots
    const char* eb = ebuf[cur];
    const int arow = c * 128;
    const int sw = (c & 7) << 4;
    float4 fa0 = *(const float4*)(eb + arow + ((g * 32) ^ sw));
    float4 fa1 = *(const float4*)(eb + arow + ((g * 32 + 16) ^ sw));
    short8 af;
    af[0] = (short)f2bf(fa0.x); af[1] = (short)f2bf(fa0.y);
    af[2] = (short)f2bf(fa0.z); af[3] = (short)f2bf(fa0.w);
    af[4] = (short)f2bf(fa1.x); af[5] = (short)f2bf(fa1.y);
    af[6] = (short)f2bf(fa1.z); af[7] = (short)f2bf(fa1.w);

    // B fragments + MFMA (3 col-fragments for this wave's quarter)
    const char* wb = wbuf[cur];
#pragma unroll
    for (int fi = 0; fi < 3; ++fi) {
      const int fg = w * 3 + fi;
      const int col = (fg >> 2) * 64 + (fg & 3) * 16 + c;
      const int kc = (col & 3) ^ ((col >> 2) & 3);
      short8 bf = *(const short8*)(wb + col * 64 + ((g ^ kc) << 4));
      acc[fi] = mfma16(af, bf, acc[fi]);
    }

    __syncthreads();   // full drain; 3 co-resident blocks overlap it
    cur ^= 1;
  }

  // ---- store: Q (scaled), K direct; V via LDS transpose ----
#pragma unroll
  for (int fi = 0; fi < 3; ++fi) {
    const int fg = w * 3 + fi;
    const int m = fg >> 2, cf = fg & 3;
    const int col = cf * 16 + c;
#pragma unroll
    for (int r = 0; r < 4; ++r) {
      const int rloc = g * 4 + r;
      const size_t grow = (size_t)(rbase + rloc);
      const float v = acc[fi][r];
      if (m == 0)      Q[grow * AD + col] = f2bf(v * 0.125f);  // fold 1/sqrt(64)
      else if (m == 1) K[grow * AD + col] = f2bf(v);
      else             t[rloc][col] = f2bf(v);
    }
  }
  __syncthreads();
  // ---- V transpose epilogue (R10-passing 16-row form) ----
  const int bb = blockIdx.x >> 8;             // 256 blocks per batch
  const int sb = (blockIdx.x & 255) * 16;
  const int s = threadIdx.x & 15;
  const int d0 = threadIdx.x >> 4;            // 0..15
#pragma unroll
  for (int it = 0; it < 4; ++it) {
    const int d = it * 16 + d0;
    Vt[(size_t)(bb * AD + d) * SEQ + sb + s] = t[s][d];
  }
#undef PSTAGE
}

// ---------------- Kernel 2: flash attention partials (unchanged, PASSING) ----
__global__ __launch_bounds__(256, 3) void flash_part(const u16* __restrict__ Q,
                                                     const u16* __restrict__ K,
                                                     const u16* __restrict__ Vt,
                                                     float* __restrict__ opart,
                                                     float* __restrict__ ml) {
  const int bx = blockIdx.x;
  const int b = bx & 3;
  const int u = bx >> 2;
  int bq, c;
  if (u < 16)       { bq = 16 + u;        c = 0; }   // 16-tile blocks first
  else if (u < 32)  { bq = 32 + (u - 16); c = 0; }
  else if (u < 48)  { bq = 32 + (u - 32); c = 1; }
  else if (u < 64)  { bq = 48 + (u - 48); c = 0; }
  else if (u < 80)  { bq = 48 + (u - 64); c = 1; }
  else if (u < 96)  { bq = 48 + (u - 80); c = 2; }
  else { int d = u - 96; bq = (d >> 4) * 16 + 15 - (d & 15); c = d >> 4; }
  const int t0 = c * CHK;
  const int tend = (c == (bq >> 4)) ? (bq + 1) : (t0 + CHK);  // diag: up to tile bq

  const int w = threadIdx.x >> 6;
  const int lane = threadIdx.x & 63;
  const int g = lane >> 4, cl = lane & 15;
  const int r8 = lane >> 3, c16 = lane & 7;   // staging decomposition
  const int q0 = bq * 64 + w * 16;

  const u16* Qb = Q + (size_t)b * SEQ * AD;
  const u16* Kb = K + (size_t)b * SEQ * AD;
  const u16* Vb = Vt + (size_t)b * AD * SEQ;

  __shared__ __align__(16) u16 kbuf[2][64 * 64];
  __shared__ __align__(16) u16 vbuf[2][64 * 64];
  __shared__ __align__(16) u16 plds_all[4][16 * 64];
  char* plds = (char*)plds_all[w];
  const int swz = (cl & 7) << 4;
  const int prow = cl * 128;
  const int fsw = (cl & 7);                    // fragment-read row swizzle key

  const short8 qf0 = *(const short8*)(Qb + (size_t)(q0 + cl) * AD + g * 8);
  const short8 qf1 = *(const short8*)(Qb + (size_t)(q0 + cl) * AD + 32 + g * 8);

  float mrow = -INFINITY, lrow = 0.f;
  f32x4 o[4];
#pragma unroll
  for (int cf = 0; cf < 4; cf++)
#pragma unroll
    for (int r = 0; r < 4; r++) o[cf][r] = 0.f;

#define STAGE(bufi, tt) do {                                                   \
    const int kvb = (tt) * 64;                                                 \
    const int row0 = w * 16 + r8, row1 = w * 16 + 8 + r8;                      \
    gload16(Kb + (size_t)(kvb + row0) * AD + ((c16 ^ r8) << 3),                \
            &kbuf[bufi][(w * 16) * 64]);                                       \
    gload16(Kb + (size_t)(kvb + row1) * AD + ((c16 ^ r8) << 3),                \
            &kbuf[bufi][(w * 16 + 8) * 64]);                                   \
    gload16(Vb + (size_t)row0 * SEQ + kvb + ((c16 ^ r8) << 3),                 \
            &vbuf[bufi][(w * 16) * 64]);                                       \
    gload16(Vb + (size_t)row1 * SEQ + kvb + ((c16 ^ r8) << 3),                 \
            &vbuf[bufi][(w * 16 + 8) * 64]);                                   \
  } while (0)

  STAGE(0, t0);
  __syncthreads();

  int cur = 0;
  for (int t = t0; t < tend; ++t) {
    const int kv0 = t * 64;
    if (t + 1 < tend) STAGE(cur ^ 1, t + 1);

    const char* kb = (const char*)kbuf[cur];
    const char* vb = (const char*)vbuf[cur];

    short8 kf0[4], kf1[4];
#pragma unroll
    for (int cf = 0; cf < 4; cf++) {
      const int kr = (cf * 16 + cl) * 128;
      kf0[cf] = *(const short8*)(kb + kr + ((g ^ fsw) << 4));
      kf1[cf] = *(const short8*)(kb + kr + (((4 + g) ^ fsw) << 4));
    }

    f32x4 s4[4];
#pragma unroll
    for (int cf = 0; cf < 4; cf++) {
      f32x4 z; z[0] = z[1] = z[2] = z[3] = 0.f;
      z = mfma16(kf0[cf], qf0, z);
      s4[cf] = mfma16(kf1[cf], qf1, z);
    }

    if (t == bq) {
#pragma unroll
      for (int cf = 0; cf < 4; cf++) {
        const int kvb2 = kv0 + cf * 16 + g * 4;
#pragma unroll
        for (int r = 0; r < 4; r++)
          s4[cf][r] = (kvb2 + r <= q0 + cl) ? s4[cf][r] : -INFINITY;
      }
    }

    float tm[4];
#pragma unroll
    for (int cf = 0; cf < 4; cf++)
      tm[cf] = fmaxf(fmaxf(s4[cf][0], s4[cf][1]), fmaxf(s4[cf][2], s4[cf][3]));
    float mt = fmaxf(fmaxf(tm[0], tm[1]), fmaxf(tm[2], tm[3]));
    mt = xor16_max(mt);
    mt = xor32_max(mt);

    if (!__all(mt <= mrow + 8.0f)) {
      const float mn = fmaxf(mrow, mt);
      const float corr = __expf(mrow - mn);
      mrow = mn;
      lrow *= corr;
      float cb[4];
#pragma unroll
      for (int r = 0; r < 4; r++) cb[r] = __shfl(corr, g * 20 + r);
#pragma unroll
      for (int cf = 0; cf < 4; cf++) {
        o[cf][0] *= cb[0]; o[cf][1] *= cb[1];
        o[cf][2] *= cb[2]; o[cf][3] *= cb[3];
      }
    }

    float rs = 0.f;
#pragma unroll
    for (int cf = 0; cf < 4; cf++) {
      const float p0 = __expf(s4[cf][0] - mrow);
      const float p1 = __expf(s4[cf][1] - mrow);
      const float p2 = __expf(s4[cf][2] - mrow);
      const float p3 = __expf(s4[cf][3] - mrow);
      rs += (p0 + p1) + (p2 + p3);
      uint2 val;
      val.x = cvt_pk_bf16(p0, p1);
      val.y = cvt_pk_bf16(p2, p3);
      *(uint2*)(plds + prow + (((cf * 32) + (g * 8)) ^ swz)) = val;
    }
    rs = xor16_sum(rs);
    rs = xor32_sum(rs);
    lrow += rs;

    // Fence: P ds_writes above are uint2-typed, PV ds_reads below are
    // short8-typed -- TBAA says no-alias; keep the RAW pair ordered.
    asm volatile("" ::: "memory");

#pragma unroll
    for (int f = 0; f < 2; ++f) {
      const short8 pf = *(const short8*)(plds + prow + ((f * 64 + g * 16) ^ swz));
#pragma unroll
      for (int cf = 0; cf < 4; cf++) {
        const int vr = (cf * 16 + cl) * 128;
        const short8 vfa = *(const short8*)(vb + vr + (((f * 4 + g) ^ fsw) << 4));
        o[cf] = mfma16(pf, vfa, o[cf]);
      }
    }

    __syncthreads();
    cur ^= 1;
  }

  const int qg = bq * 4 + w;
  const int k2 = qg >> 6;
  const int slot = b * 640 + 32 * k2 * (k2 + 1) + (qg & 63) * (k2 + 1) + c;

  if (lane < 16) {
    ml[(size_t)slot * 32 + cl * 2 + 0] = mrow;
    ml[(size_t)slot * 32 + cl * 2 + 1] = lrow;
  }
#pragma unroll
  for (int cf = 0; cf < 4; cf++)
#pragma unroll
    for (int r = 0; r < 4; r++)
      opart[(size_t)slot * 1024 + (g * 4 + r) * 64 + cf * 16 + cl] = o[cf][r];
#undef STAGE
}

// ---------------- Kernel 3: combine partials (unchanged) --------------------
__global__ __launch_bounds__(256) void combine_kernel(const float* __restrict__ opart,
                                                      const float* __restrict__ ml,
                                                      float* __restrict__ out) {
  const int tid = threadIdx.x;
  const int row = blockIdx.x * 16 + (tid >> 4);   // 0..16383
  const int d = (tid & 15) * 4;
  const int b = row >> 12;
  const int rowb = row & 4095;
  const int qg = rowb >> 4;
  const int r = rowb & 15;
  const int k2 = qg >> 6;
  const int nc = k2 + 1;
  const int sbase = b * 640 + 32 * k2 * (k2 + 1) + (qg & 63) * nc;

  float M = -INFINITY;
  float ms[4], ls[4];
  for (int cc = 0; cc < nc; cc++) {
    ms[cc] = ml[(size_t)(sbase + cc) * 32 + r * 2 + 0];
    ls[cc] = ml[(size_t)(sbase + cc) * 32 + r * 2 + 1];
    M = fmaxf(M, ms[cc]);
  }
  float L = 0.f;
  float4 acc = {0.f, 0.f, 0.f, 0.f};
  for (int cc = 0; cc < nc; cc++) {
    const float wgt = __expf(ms[cc] - M);
    L += ls[cc] * wgt;
    float4 ov = *(const float4*)(opart + (size_t)(sbase + cc) * 1024 + r * 64 + d);
    acc.x += ov.x * wgt; acc.y += ov.y * wgt;
    acc.z += ov.z * wgt; acc.w += ov.w * wgt;
  }
  const float inv = 1.0f / L;
  float4 res;
  res.x = rintf(acc.x * inv * 1.0e4f) * 1.0e-4f;
  res.y = rintf(acc.y * inv * 1.0e4f) * 1.0e-4f;
  res.z = rintf(acc.z * inv * 1.0e4f) * 1.0e-4f;
  res.w = rintf(acc.w * inv * 1.0e4f) * 1.0e-4f;
  *(float4*)(out + (size_t)row * AD + d) = res;
}

extern "C" void kernel_launch(void* const* d_in, const int* in_sizes, int n_in,
                              void* d_out, int out_size, void* d_ws, size_t ws_size,
                              hipStream_t stream) {
  const float* emb = (const float*)d_in[0];
  const float* Wq  = (const float*)d_in[1];
  const float* Wk  = (const float*)d_in[2];
  const float* Wv  = (const float*)d_in[3];
  float* out = (float*)d_out;

  char* ws = (char*)d_ws;
  u16* Wt = (u16*)ws;                               // 294912 B
  u16* Q  = (u16*)(ws + 294912);                    // 2 MiB each
  u16* K  = Q + (size_t)BS * AD;
  u16* Vt = K + (size_t)BS * AD;
  float* opart = (float*)(ws + 294912 + 3 * (size_t)BS * AD * 2);  // 2560*4KB
  float* ml    = opart + (size_t)2560 * 1024;                      // 2560*128B

  wt_kernel<<<(3 * AD * EMB + 255) / 256, 256, 0, stream>>>(Wq, Wk, Wv, Wt);
  proj_kernel<<<BS / 16, 256, 0, stream>>>(emb, Wt, Q, K, Vt);
  flash_part<<<640, 256, 0, stream>>>(Q, K, Vt, opart, ml);
  combine_kernel<<<BS / 16, 256, 0, stream>>>(opart, ml, out);
}

// Round 16
// 58.955 us; speedup vs baseline: 1.1267x; 1.1267x over previous
//
#include <hip/hip_runtime.h>

#define NB 4
#define SEQ 4096
#define EMB 768
#define AD 64
#define BS (NB*SEQ)
#define CHK 16   // kv tiles (of 64) per chunk

typedef short short8 __attribute__((ext_vector_type(8)));
typedef float f32x4 __attribute__((ext_vector_type(4)));
typedef int   i32x2 __attribute__((ext_vector_type(2)));
typedef unsigned short u16;

__device__ __forceinline__ u16 f2bf(float f) {
  union { float f; unsigned u; } v; v.f = f;
  unsigned u = v.u;
  unsigned r = (u + 0x7FFFu + ((u >> 16) & 1u)) >> 16;  // RNE
  return (u16)r;
}

__device__ __forceinline__ unsigned cvt_pk_bf16(float lo, float hi) {
  unsigned r;
  asm("v_cvt_pk_bf16_f32 %0, %1, %2" : "=v"(r) : "v"(lo), "v"(hi));
  return r;
}

__device__ __forceinline__ f32x4 mfma16(short8 a, short8 b, f32x4 c) {
  return __builtin_amdgcn_mfma_f32_16x16x32_bf16(a, b, c, 0, 0, 0);
}

// async global->LDS, 16B per lane; LDS dest = uniform base + lane*16
__device__ __forceinline__ void gload16(const u16* g, u16* l) {
  __builtin_amdgcn_global_load_lds(
      (const __attribute__((address_space(1))) unsigned*)g,
      (__attribute__((address_space(3))) unsigned*)l, 16, 0, 0);
}

__device__ __forceinline__ float xor16_max(float x) {
#if __has_builtin(__builtin_amdgcn_permlane16_swap)
  i32x2 r = __builtin_amdgcn_permlane16_swap(__float_as_int(x), __float_as_int(x), false, false);
  return fmaxf(__int_as_float(r[0]), __int_as_float(r[1]));
#else
  return fmaxf(x, __shfl_xor(x, 16));
#endif
}
__device__ __forceinline__ float xor16_sum(float x) {
#if __has_builtin(__builtin_amdgcn_permlane16_swap)
  i32x2 r = __builtin_amdgcn_permlane16_swap(__float_as_int(x), __float_as_int(x), false, false);
  return __int_as_float(r[0]) + __int_as_float(r[1]);
#else
  return x + __shfl_xor(x, 16);
#endif
}
__device__ __forceinline__ float xor32_max(float x) {
#if __has_builtin(__builtin_amdgcn_permlane32_swap)
  i32x2 r = __builtin_amdgcn_permlane32_swap(__float_as_int(x), __float_as_int(x), false, false);
  return fmaxf(__int_as_float(r[0]), __int_as_float(r[1]));
#else
  return fmaxf(x, __shfl_xor(x, 32));
#endif
}
__device__ __forceinline__ float xor32_sum(float x) {
#if __has_builtin(__builtin_amdgcn_permlane32_swap)
  i32x2 r = __builtin_amdgcn_permlane32_swap(__float_as_int(x), __float_as_int(x), false, false);
  return __int_as_float(r[0]) + __int_as_float(r[1]);
#else
  return x + __shfl_xor(x, 32);
#endif
}

// ---------------- Kernel 0: weight transpose + bf16 cast (PASSING) ----------
// Wt[(m*64 + col)*768 + e] = W_m[e*64 + col]
__global__ void wt_kernel(const float* __restrict__ Wq, const float* __restrict__ Wk,
                          const float* __restrict__ Wv, u16* __restrict__ Wt) {
  int idx = blockIdx.x * 256 + threadIdx.x;
  if (idx >= 3 * AD * EMB) return;
  int m   = idx / (AD * EMB);
  int rem = idx - m * (AD * EMB);
  int col = rem / EMB;
  int e   = rem - col * EMB;
  const float* W = (m == 0) ? Wq : (m == 1) ? Wk : Wv;
  Wt[idx] = f2bf(W[e * AD + col]);
}

// ---------------- Kernel 1: QKV projection, LDS-staged GEMM v7 --------------
// R14-passing geometry (block = 32 rows x 512 thr, grid 512, 2 blocks/CU)
// with BK=64: each iteration stages TWO BK=32 sub-buffers (identical R14
// formulas per sub-buffer, kt = 2*it+kk), computes both, ONE barrier.
// 12 barriers instead of 24; accumulation order preserved exactly.
__global__ __launch_bounds__(512) void proj_kernel(const float* __restrict__ emb,
                                                   const u16* __restrict__ Wt,
                                                   u16* __restrict__ Q, u16* __restrict__ K,
                                                   u16* __restrict__ Vt) {
  const int w = threadIdx.x >> 6;
  const int lane = threadIdx.x & 63;
  const int g = lane >> 4, c = lane & 15;
  const int wr = w & 1;                 // row group (16 rows)
  const int cq = w >> 1;                // col quarter (3 fragments)
  const int rbase = blockIdx.x * 32;

  __shared__ __align__(16) char ebuf[2][2][4096];    // [buf][kk][32 rows][128B], key row&7
  __shared__ __align__(16) char wbuf[2][2][12288];   // [buf][kk][192 cols][64B], key (col&3)^((col>>2)&3)
  __shared__ u16 t[32][65];                          // V transpose staging

  const int r8 = lane >> 3, j8 = lane & 7;        // emb staging decomposition
  const int c4 = lane >> 2, j4 = lane & 3;        // wt staging decomposition

  f32x4 acc[3];
#pragma unroll
  for (int fi = 0; fi < 3; ++fi)
#pragma unroll
    for (int r = 0; r < 4; ++r) acc[fi][r] = 0.f;

  // staging of ONE BK=32 sub-buffer, 2 gloads per wave (R14-identical):
  //   all w: wt col-group w;  w<4: + emb rows w*8;  w>=4: + wt col-group 4+w
#define PSTAGE(bufi, kk, kt) do {                                              \
    { const int col = w * 16 + c4;                                             \
      const int kc = (col & 3) ^ ((col >> 2) & 3);                             \
      gload16(Wt + (size_t)col * EMB + (kt) * 32 + ((j4 ^ kc) << 3),           \
              (u16*)(wbuf[bufi][kk] + w * 1024)); }                            \
    if (w < 4) {                                                               \
      gload16((const u16*)(emb + (size_t)(rbase + w * 8 + r8) * EMB            \
                           + (kt) * 32 + ((j8 ^ r8) << 2)),                    \
              (u16*)(ebuf[bufi][kk] + w * 1024));                              \
    } else {                                                                   \
      const int col = (4 + w) * 16 + c4;                                       \
      const int kc = (col & 3) ^ ((col >> 2) & 3);                             \
      gload16(Wt + (size_t)col * EMB + (kt) * 32 + ((j4 ^ kc) << 3),           \
              (u16*)(wbuf[bufi][kk] + (4 + w) * 1024));                        \
    }                                                                          \
  } while (0)

  PSTAGE(0, 0, 0);
  PSTAGE(0, 1, 1);
  __syncthreads();

  int cur = 0;
  for (int it = 0; it < 12; ++it) {
    if (it + 1 < 12) {
      PSTAGE(cur ^ 1, 0, 2 * it + 2);
      PSTAGE(cur ^ 1, 1, 2 * it + 3);
    }

#pragma unroll
    for (int kk = 0; kk < 2; ++kk) {
      // A fragment: row wr*16+c, 8 floats (k = g*8..g*8+8), swizzled slots
      const char* eb = ebuf[cur][kk];
      const int arow = (wr * 16 + c) * 128;
      const int sw = (c & 7) << 4;
      float4 fa0 = *(const float4*)(eb + arow + ((g * 32) ^ sw));
      float4 fa1 = *(const float4*)(eb + arow + ((g * 32 + 16) ^ sw));
      short8 af;
      af[0] = (short)f2bf(fa0.x); af[1] = (short)f2bf(fa0.y);
      af[2] = (short)f2bf(fa0.z); af[3] = (short)f2bf(fa0.w);
      af[4] = (short)f2bf(fa1.x); af[5] = (short)f2bf(fa1.y);
      af[6] = (short)f2bf(fa1.z); af[7] = (short)f2bf(fa1.w);

      // B fragments + MFMA (3 col-fragments for this wave's quarter)
      const char* wb = wbuf[cur][kk];
#pragma unroll
      for (int fi = 0; fi < 3; ++fi) {
        const int fg = cq * 3 + fi;
        const int col = (fg >> 2) * 64 + (fg & 3) * 16 + c;
        const int kc = (col & 3) ^ ((col >> 2) & 3);
        short8 bf = *(const short8*)(wb + col * 64 + ((g ^ kc) << 4));
        acc[fi] = mfma16(af, bf, acc[fi]);
      }
    }

    __syncthreads();   // one barrier per 2 k-steps; co-resident block overlaps
    cur ^= 1;
  }

  // ---- store: Q (scaled), K direct; V via LDS transpose ----
#pragma unroll
  for (int fi = 0; fi < 3; ++fi) {
    const int fg = cq * 3 + fi;
    const int m = fg >> 2, cf = fg & 3;
    const int col = cf * 16 + c;
#pragma unroll
    for (int r = 0; r < 4; ++r) {
      const int rloc = wr * 16 + g * 4 + r;
      const size_t grow = (size_t)(rbase + rloc);
      const float v = acc[fi][r];
      if (m == 0)      Q[grow * AD + col] = f2bf(v * 0.125f);  // fold 1/sqrt(64)
      else if (m == 1) K[grow * AD + col] = f2bf(v);
      else             t[rloc][col] = f2bf(v);
    }
  }
  __syncthreads();
  const int bb = blockIdx.x >> 7;             // 128 blocks per batch
  const int sb = (blockIdx.x & 127) * 32;
  const int s = threadIdx.x & 31;
  const int d0 = threadIdx.x >> 5;            // 0..15
#pragma unroll
  for (int it = 0; it < 4; ++it) {
    const int d = it * 16 + d0;
    Vt[(size_t)(bb * AD + d) * SEQ + sb + s] = t[s][d];
  }
#undef PSTAGE
}

// ---------------- Kernel 2: flash attention partials (unchanged, PASSING) ----
__global__ __launch_bounds__(256, 3) void flash_part(const u16* __restrict__ Q,
                                                     const u16* __restrict__ K,
                                                     const u16* __restrict__ Vt,
                                                     float* __restrict__ opart,
                                                     float* __restrict__ ml) {
  const int bx = blockIdx.x;
  const int b = bx & 3;
  const int u = bx >> 2;
  int bq, c;
  if (u < 16)       { bq = 16 + u;        c = 0; }   // 16-tile blocks first
  else if (u < 32)  { bq = 32 + (u - 16); c = 0; }
  else if (u < 48)  { bq = 32 + (u - 32); c = 1; }
  else if (u < 64)  { bq = 48 + (u - 48); c = 0; }
  else if (u < 80)  { bq = 48 + (u - 64); c = 1; }
  else if (u < 96)  { bq = 48 + (u - 80); c = 2; }
  else { int d = u - 96; bq = (d >> 4) * 16 + 15 - (d & 15); c = d >> 4; }
  const int t0 = c * CHK;
  const int tend = (c == (bq >> 4)) ? (bq + 1) : (t0 + CHK);  // diag: up to tile bq

  const int w = threadIdx.x >> 6;
  const int lane = threadIdx.x & 63;
  const int g = lane >> 4, cl = lane & 15;
  const int r8 = lane >> 3, c16 = lane & 7;   // staging decomposition
  const int q0 = bq * 64 + w * 16;

  const u16* Qb = Q + (size_t)b * SEQ * AD;
  const u16* Kb = K + (size_t)b * SEQ * AD;
  const u16* Vb = Vt + (size_t)b * AD * SEQ;

  __shared__ __align__(16) u16 kbuf[2][64 * 64];
  __shared__ __align__(16) u16 vbuf[2][64 * 64];
  __shared__ __align__(16) u16 plds_all[4][16 * 64];
  char* plds = (char*)plds_all[w];
  const int swz = (cl & 7) << 4;
  const int prow = cl * 128;
  const int fsw = (cl & 7);                    // fragment-read row swizzle key

  const short8 qf0 = *(const short8*)(Qb + (size_t)(q0 + cl) * AD + g * 8);
  const short8 qf1 = *(const short8*)(Qb + (size_t)(q0 + cl) * AD + 32 + g * 8);

  float mrow = -INFINITY, lrow = 0.f;
  f32x4 o[4];
#pragma unroll
  for (int cf = 0; cf < 4; cf++)
#pragma unroll
    for (int r = 0; r < 4; r++) o[cf][r] = 0.f;

#define STAGE(bufi, tt) do {                                                   \
    const int kvb = (tt) * 64;                                                 \
    const int row0 = w * 16 + r8, row1 = w * 16 + 8 + r8;                      \
    gload16(Kb + (size_t)(kvb + row0) * AD + ((c16 ^ r8) << 3),                \
            &kbuf[bufi][(w * 16) * 64]);                                       \
    gload16(Kb + (size_t)(kvb + row1) * AD + ((c16 ^ r8) << 3),                \
            &kbuf[bufi][(w * 16 + 8) * 64]);                                   \
    gload16(Vb + (size_t)row0 * SEQ + kvb + ((c16 ^ r8) << 3),                 \
            &vbuf[bufi][(w * 16) * 64]);                                       \
    gload16(Vb + (size_t)row1 * SEQ + kvb + ((c16 ^ r8) << 3),                 \
            &vbuf[bufi][(w * 16 + 8) * 64]);                                   \
  } while (0)

  STAGE(0, t0);
  __syncthreads();

  int cur = 0;
  for (int t = t0; t < tend; ++t) {
    const int kv0 = t * 64;
    if (t + 1 < tend) STAGE(cur ^ 1, t + 1);

    const char* kb = (const char*)kbuf[cur];
    const char* vb = (const char*)vbuf[cur];

    short8 kf0[4], kf1[4];
#pragma unroll
    for (int cf = 0; cf < 4; cf++) {
      const int kr = (cf * 16 + cl) * 128;
      kf0[cf] = *(const short8*)(kb + kr + ((g ^ fsw) << 4));
      kf1[cf] = *(const short8*)(kb + kr + (((4 + g) ^ fsw) << 4));
    }

    f32x4 s4[4];
#pragma unroll
    for (int cf = 0; cf < 4; cf++) {
      f32x4 z; z[0] = z[1] = z[2] = z[3] = 0.f;
      z = mfma16(kf0[cf], qf0, z);
      s4[cf] = mfma16(kf1[cf], qf1, z);
    }

    if (t == bq) {
#pragma unroll
      for (int cf = 0; cf < 4; cf++) {
        const int kvb2 = kv0 + cf * 16 + g * 4;
#pragma unroll
        for (int r = 0; r < 4; r++)
          s4[cf][r] = (kvb2 + r <= q0 + cl) ? s4[cf][r] : -INFINITY;
      }
    }

    float tm[4];
#pragma unroll
    for (int cf = 0; cf < 4; cf++)
      tm[cf] = fmaxf(fmaxf(s4[cf][0], s4[cf][1]), fmaxf(s4[cf][2], s4[cf][3]));
    float mt = fmaxf(fmaxf(tm[0], tm[1]), fmaxf(tm[2], tm[3]));
    mt = xor16_max(mt);
    mt = xor32_max(mt);

    if (!__all(mt <= mrow + 8.0f)) {
      const float mn = fmaxf(mrow, mt);
      const float corr = __expf(mrow - mn);
      mrow = mn;
      lrow *= corr;
      float cb[4];
#pragma unroll
      for (int r = 0; r < 4; r++) cb[r] = __shfl(corr, g * 20 + r);
#pragma unroll
      for (int cf = 0; cf < 4; cf++) {
        o[cf][0] *= cb[0]; o[cf][1] *= cb[1];
        o[cf][2] *= cb[2]; o[cf][3] *= cb[3];
      }
    }

    float rs = 0.f;
#pragma unroll
    for (int cf = 0; cf < 4; cf++) {
      const float p0 = __expf(s4[cf][0] - mrow);
      const float p1 = __expf(s4[cf][1] - mrow);
      const float p2 = __expf(s4[cf][2] - mrow);
      const float p3 = __expf(s4[cf][3] - mrow);
      rs += (p0 + p1) + (p2 + p3);
      uint2 val;
      val.x = cvt_pk_bf16(p0, p1);
      val.y = cvt_pk_bf16(p2, p3);
      *(uint2*)(plds + prow + (((cf * 32) + (g * 8)) ^ swz)) = val;
    }
    rs = xor16_sum(rs);
    rs = xor32_sum(rs);
    lrow += rs;

    // Fence: P ds_writes above are uint2-typed, PV ds_reads below are
    // short8-typed -- TBAA says no-alias; keep the RAW pair ordered.
    asm volatile("" ::: "memory");

#pragma unroll
    for (int f = 0; f < 2; ++f) {
      const short8 pf = *(const short8*)(plds + prow + ((f * 64 + g * 16) ^ swz));
#pragma unroll
      for (int cf = 0; cf < 4; cf++) {
        const int vr = (cf * 16 + cl) * 128;
        const short8 vfa = *(const short8*)(vb + vr + (((f * 4 + g) ^ fsw) << 4));
        o[cf] = mfma16(pf, vfa, o[cf]);
      }
    }

    __syncthreads();
    cur ^= 1;
  }

  const int qg = bq * 4 + w;
  const int k2 = qg >> 6;
  const int slot = b * 640 + 32 * k2 * (k2 + 1) + (qg & 63) * (k2 + 1) + c;

  if (lane < 16) {
    ml[(size_t)slot * 32 + cl * 2 + 0] = mrow;
    ml[(size_t)slot * 32 + cl * 2 + 1] = lrow;
  }
#pragma unroll
  for (int cf = 0; cf < 4; cf++)
#pragma unroll
    for (int r = 0; r < 4; r++)
      opart[(size_t)slot * 1024 + (g * 4 + r) * 64 + cf * 16 + cl] = o[cf][r];
#undef STAGE
}

// ---------------- Kernel 3: combine partials (unchanged) --------------------
__global__ __launch_bounds__(256) void combine_kernel(const float* __restrict__ opart,
                                                      const float* __restrict__ ml,
                                                      float* __restrict__ out) {
  const int tid = threadIdx.x;
  const int row = blockIdx.x * 16 + (tid >> 4);   // 0..16383
  const int d = (tid & 15) * 4;
  const int b = row >> 12;
  const int rowb = row & 4095;
  const int qg = rowb >> 4;
  const int r = rowb & 15;
  const int k2 = qg >> 6;
  const int nc = k2 + 1;
  const int sbase = b * 640 + 32 * k2 * (k2 + 1) + (qg & 63) * nc;

  float M = -INFINITY;
  float ms[4], ls[4];
  for (int cc = 0; cc < nc; cc++) {
    ms[cc] = ml[(size_t)(sbase + cc) * 32 + r * 2 + 0];
    ls[cc] = ml[(size_t)(sbase + cc) * 32 + r * 2 + 1];
    M = fmaxf(M, ms[cc]);
  }
  float L = 0.f;
  float4 acc = {0.f, 0.f, 0.f, 0.f};
  for (int cc = 0; cc < nc; cc++) {
    const float wgt = __expf(ms[cc] - M);
    L += ls[cc] * wgt;
    float4 ov = *(const float4*)(opart + (size_t)(sbase + cc) * 1024 + r * 64 + d);
    acc.x += ov.x * wgt; acc.y += ov.y * wgt;
    acc.z += ov.z * wgt; acc.w += ov.w * wgt;
  }
  const float inv = 1.0f / L;
  float4 res;
  res.x = rintf(acc.x * inv * 1.0e4f) * 1.0e-4f;
  res.y = rintf(acc.y * inv * 1.0e4f) * 1.0e-4f;
  res.z = rintf(acc.z * inv * 1.0e4f) * 1.0e-4f;
  res.w = rintf(acc.w * inv * 1.0e4f) * 1.0e-4f;
  *(float4*)(out + (size_t)row * AD + d) = res;
}

extern "C" void kernel_launch(void* const* d_in, const int* in_sizes, int n_in,
                              void* d_out, int out_size, void* d_ws, size_t ws_size,
                              hipStream_t stream) {
  const float* emb = (const float*)d_in[0];
  const float* Wq  = (const float*)d_in[1];
  const float* Wk  = (const float*)d_in[2];
  const float* Wv  = (const float*)d_in[3];
  float* out = (float*)d_out;

  char* ws = (char*)d_ws;
  u16* Wt = (u16*)ws;                               // 294912 B
  u16* Q  = (u16*)(ws + 294912);                    // 2 MiB each
  u16* K  = Q + (size_t)BS * AD;
  u16* Vt = K + (size_t)BS * AD;
  float* opart = (float*)(ws + 294912 + 3 * (size_t)BS * AD * 2);  // 2560*4KB
  float* ml    = opart + (size_t)2560 * 1024;                      // 2560*128B

  wt_kernel<<<(3 * AD * EMB + 255) / 256, 256, 0, stream>>>(Wq, Wk, Wv, Wt);
  proj_kernel<<<BS / 32, 512, 0, stream>>>(emb, Wt, Q, K, Vt);
  flash_part<<<640, 256, 0, stream>>>(Q, K, Vt, opart, ml);
  combine_kernel<<<BS / 16, 256, 0, stream>>>(opart, ml, out);
}

// Round 17
// 57.945 us; speedup vs baseline: 1.1463x; 1.0174x over previous
//
#include <hip/hip_runtime.h>

#define NB 4
#define SEQ 4096
#define EMB 768
#define AD 64
#define BS (NB*SEQ)
#define CHK 16   // kv tiles (of 64) per chunk

typedef short short8 __attribute__((ext_vector_type(8)));
typedef float f32x4 __attribute__((ext_vector_type(4)));
typedef int   i32x2 __attribute__((ext_vector_type(2)));
typedef unsigned short u16;

__device__ __forceinline__ u16 f2bf(float f) {
  union { float f; unsigned u; } v; v.f = f;
  unsigned u = v.u;
  unsigned r = (u + 0x7FFFu + ((u >> 16) & 1u)) >> 16;  // RNE
  return (u16)r;
}

__device__ __forceinline__ float bf2f(u16 b) {
  union { unsigned u; float f; } v; v.u = ((unsigned)b) << 16;
  return v.f;
}

__device__ __forceinline__ unsigned cvt_pk_bf16(float lo, float hi) {
  unsigned r;
  asm("v_cvt_pk_bf16_f32 %0, %1, %2" : "=v"(r) : "v"(lo), "v"(hi));
  return r;
}

__device__ __forceinline__ f32x4 mfma16(short8 a, short8 b, f32x4 c) {
  return __builtin_amdgcn_mfma_f32_16x16x32_bf16(a, b, c, 0, 0, 0);
}

// async global->LDS, 16B per lane; LDS dest = uniform base + lane*16
__device__ __forceinline__ void gload16(const u16* g, u16* l) {
  __builtin_amdgcn_global_load_lds(
      (const __attribute__((address_space(1))) unsigned*)g,
      (__attribute__((address_space(3))) unsigned*)l, 16, 0, 0);
}

__device__ __forceinline__ float xor16_max(float x) {
#if __has_builtin(__builtin_amdgcn_permlane16_swap)
  i32x2 r = __builtin_amdgcn_permlane16_swap(__float_as_int(x), __float_as_int(x), false, false);
  return fmaxf(__int_as_float(r[0]), __int_as_float(r[1]));
#else
  return fmaxf(x, __shfl_xor(x, 16));
#endif
}
__device__ __forceinline__ float xor16_sum(float x) {
#if __has_builtin(__builtin_amdgcn_permlane16_swap)
  i32x2 r = __builtin_amdgcn_permlane16_swap(__float_as_int(x), __float_as_int(x), false, false);
  return __int_as_float(r[0]) + __int_as_float(r[1]);
#else
  return x + __shfl_xor(x, 16);
#endif
}
__device__ __forceinline__ float xor32_max(float x) {
#if __has_builtin(__builtin_amdgcn_permlane32_swap)
  i32x2 r = __builtin_amdgcn_permlane32_swap(__float_as_int(x), __float_as_int(x), false, false);
  return fmaxf(__int_as_float(r[0]), __int_as_float(r[1]));
#else
  return fmaxf(x, __shfl_xor(x, 32));
#endif
}
__device__ __forceinline__ float xor32_sum(float x) {
#if __has_builtin(__builtin_amdgcn_permlane32_swap)
  i32x2 r = __builtin_amdgcn_permlane32_swap(__float_as_int(x), __float_as_int(x), false, false);
  return __int_as_float(r[0]) + __int_as_float(r[1]);
#else
  return x + __shfl_xor(x, 32);
#endif
}

// ---------------- Kernel 0: weight transpose + bf16 cast (PASSING) ----------
// Wt[(m*64 + col)*768 + e] = W_m[e*64 + col]
__global__ void wt_kernel(const float* __restrict__ Wq, const float* __restrict__ Wk,
                          const float* __restrict__ Wv, u16* __restrict__ Wt) {
  int idx = blockIdx.x * 256 + threadIdx.x;
  if (idx >= 3 * AD * EMB) return;
  int m   = idx / (AD * EMB);
  int rem = idx - m * (AD * EMB);
  int col = rem / EMB;
  int e   = rem - col * EMB;
  const float* W = (m == 0) ? Wq : (m == 1) ? Wk : Wv;
  Wt[idx] = f2bf(W[e * AD + col]);
}

// ---------------- Kernel 1: QKV projection, LDS-staged GEMM v7 --------------
// R16-passing geometry (block = 32 rows x 512 thr, grid 512, BK=64, 12
// barriers). ONLY change: A-fragment bf16 conversion via v_cvt_pk_bf16_f32
// (same RNE rounding, 4 ops instead of ~28 on the LDS->MFMA critical path).
__global__ __launch_bounds__(512) void proj_kernel(const float* __restrict__ emb,
                                                   const u16* __restrict__ Wt,
                                                   u16* __restrict__ Q, u16* __restrict__ K,
                                                   u16* __restrict__ Vt) {
  const int w = threadIdx.x >> 6;
  const int lane = threadIdx.x & 63;
  const int g = lane >> 4, c = lane & 15;
  const int wr = w & 1;                 // row group (16 rows)
  const int cq = w >> 1;                // col quarter (3 fragments)
  const int rbase = blockIdx.x * 32;

  __shared__ __align__(16) char ebuf[2][2][4096];    // [buf][kk][32 rows][128B], key row&7
  __shared__ __align__(16) char wbuf[2][2][12288];   // [buf][kk][192 cols][64B], key (col&3)^((col>>2)&3)
  __shared__ u16 t[32][65];                          // V transpose staging

  const int r8 = lane >> 3, j8 = lane & 7;        // emb staging decomposition
  const int c4 = lane >> 2, j4 = lane & 3;        // wt staging decomposition

  f32x4 acc[3];
#pragma unroll
  for (int fi = 0; fi < 3; ++fi)
#pragma unroll
    for (int r = 0; r < 4; ++r) acc[fi][r] = 0.f;

#define PSTAGE(bufi, kk, kt) do {                                              \
    { const int col = w * 16 + c4;                                             \
      const int kc = (col & 3) ^ ((col >> 2) & 3);                             \
      gload16(Wt + (size_t)col * EMB + (kt) * 32 + ((j4 ^ kc) << 3),           \
              (u16*)(wbuf[bufi][kk] + w * 1024)); }                            \
    if (w < 4) {                                                               \
      gload16((const u16*)(emb + (size_t)(rbase + w * 8 + r8) * EMB            \
                           + (kt) * 32 + ((j8 ^ r8) << 2)),                    \
              (u16*)(ebuf[bufi][kk] + w * 1024));                              \
    } else {                                                                   \
      const int col = (4 + w) * 16 + c4;                                       \
      const int kc = (col & 3) ^ ((col >> 2) & 3);                             \
      gload16(Wt + (size_t)col * EMB + (kt) * 32 + ((j4 ^ kc) << 3),           \
              (u16*)(wbuf[bufi][kk] + (4 + w) * 1024));                        \
    }                                                                          \
  } while (0)

  PSTAGE(0, 0, 0);
  PSTAGE(0, 1, 1);
  __syncthreads();

  int cur = 0;
  for (int it = 0; it < 12; ++it) {
    if (it + 1 < 12) {
      PSTAGE(cur ^ 1, 0, 2 * it + 2);
      PSTAGE(cur ^ 1, 1, 2 * it + 3);
    }

#pragma unroll
    for (int kk = 0; kk < 2; ++kk) {
      // A fragment: row wr*16+c, 8 floats (k = g*8..g*8+8), swizzled slots
      const char* eb = ebuf[cur][kk];
      const int arow = (wr * 16 + c) * 128;
      const int sw = (c & 7) << 4;
      float4 fa0 = *(const float4*)(eb + arow + ((g * 32) ^ sw));
      float4 fa1 = *(const float4*)(eb + arow + ((g * 32 + 16) ^ sw));
      union { unsigned u[4]; short8 v; } uu;
      uu.u[0] = cvt_pk_bf16(fa0.x, fa0.y);
      uu.u[1] = cvt_pk_bf16(fa0.z, fa0.w);
      uu.u[2] = cvt_pk_bf16(fa1.x, fa1.y);
      uu.u[3] = cvt_pk_bf16(fa1.z, fa1.w);
      const short8 af = uu.v;

      // B fragments + MFMA (3 col-fragments for this wave's quarter)
      const char* wb = wbuf[cur][kk];
#pragma unroll
      for (int fi = 0; fi < 3; ++fi) {
        const int fg = cq * 3 + fi;
        const int col = (fg >> 2) * 64 + (fg & 3) * 16 + c;
        const int kc = (col & 3) ^ ((col >> 2) & 3);
        short8 bf = *(const short8*)(wb + col * 64 + ((g ^ kc) << 4));
        acc[fi] = mfma16(af, bf, acc[fi]);
      }
    }

    __syncthreads();   // one barrier per 2 k-steps; co-resident block overlaps
    cur ^= 1;
  }

  // ---- store: Q (scaled), K direct; V via LDS transpose ----
#pragma unroll
  for (int fi = 0; fi < 3; ++fi) {
    const int fg = cq * 3 + fi;
    const int m = fg >> 2, cf = fg & 3;
    const int col = cf * 16 + c;
#pragma unroll
    for (int r = 0; r < 4; ++r) {
      const int rloc = wr * 16 + g * 4 + r;
      const size_t grow = (size_t)(rbase + rloc);
      const float v = acc[fi][r];
      if (m == 0)      Q[grow * AD + col] = f2bf(v * 0.125f);  // fold 1/sqrt(64)
      else if (m == 1) K[grow * AD + col] = f2bf(v);
      else             t[rloc][col] = f2bf(v);
    }
  }
  __syncthreads();
  const int bb = blockIdx.x >> 7;             // 128 blocks per batch
  const int sb = (blockIdx.x & 127) * 32;
  const int s = threadIdx.x & 31;
  const int d0 = threadIdx.x >> 5;            // 0..15
#pragma unroll
  for (int it = 0; it < 4; ++it) {
    const int d = it * 16 + d0;
    Vt[(size_t)(bb * AD + d) * SEQ + sb + s] = t[s][d];
  }
#undef PSTAGE
}

// ---------------- Kernel 2: flash attention partials ------------------------
// R16-passing structure; ONLY change: opart stored as bf16 (u16) -- halves
// partial-write traffic. m/l remain fp32.
__global__ __launch_bounds__(256, 3) void flash_part(const u16* __restrict__ Q,
                                                     const u16* __restrict__ K,
                                                     const u16* __restrict__ Vt,
                                                     u16* __restrict__ opart,
                                                     float* __restrict__ ml) {
  const int bx = blockIdx.x;
  const int b = bx & 3;
  const int u = bx >> 2;
  int bq, c;
  if (u < 16)       { bq = 16 + u;        c = 0; }   // 16-tile blocks first
  else if (u < 32)  { bq = 32 + (u - 16); c = 0; }
  else if (u < 48)  { bq = 32 + (u - 32); c = 1; }
  else if (u < 64)  { bq = 48 + (u - 48); c = 0; }
  else if (u < 80)  { bq = 48 + (u - 64); c = 1; }
  else if (u < 96)  { bq = 48 + (u - 80); c = 2; }
  else { int d = u - 96; bq = (d >> 4) * 16 + 15 - (d & 15); c = d >> 4; }
  const int t0 = c * CHK;
  const int tend = (c == (bq >> 4)) ? (bq + 1) : (t0 + CHK);  // diag: up to tile bq

  const int w = threadIdx.x >> 6;
  const int lane = threadIdx.x & 63;
  const int g = lane >> 4, cl = lane & 15;
  const int r8 = lane >> 3, c16 = lane & 7;   // staging decomposition
  const int q0 = bq * 64 + w * 16;

  const u16* Qb = Q + (size_t)b * SEQ * AD;
  const u16* Kb = K + (size_t)b * SEQ * AD;
  const u16* Vb = Vt + (size_t)b * AD * SEQ;

  __shared__ __align__(16) u16 kbuf[2][64 * 64];
  __shared__ __align__(16) u16 vbuf[2][64 * 64];
  __shared__ __align__(16) u16 plds_all[4][16 * 64];
  char* plds = (char*)plds_all[w];
  const int swz = (cl & 7) << 4;
  const int prow = cl * 128;
  const int fsw = (cl & 7);                    // fragment-read row swizzle key

  const short8 qf0 = *(const short8*)(Qb + (size_t)(q0 + cl) * AD + g * 8);
  const short8 qf1 = *(const short8*)(Qb + (size_t)(q0 + cl) * AD + 32 + g * 8);

  float mrow = -INFINITY, lrow = 0.f;
  f32x4 o[4];
#pragma unroll
  for (int cf = 0; cf < 4; cf++)
#pragma unroll
    for (int r = 0; r < 4; r++) o[cf][r] = 0.f;

#define STAGE(bufi, tt) do {                                                   \
    const int kvb = (tt) * 64;                                                 \
    const int row0 = w * 16 + r8, row1 = w * 16 + 8 + r8;                      \
    gload16(Kb + (size_t)(kvb + row0) * AD + ((c16 ^ r8) << 3),                \
            &kbuf[bufi][(w * 16) * 64]);                                       \
    gload16(Kb + (size_t)(kvb + row1) * AD + ((c16 ^ r8) << 3),                \
            &kbuf[bufi][(w * 16 + 8) * 64]);                                   \
    gload16(Vb + (size_t)row0 * SEQ + kvb + ((c16 ^ r8) << 3),                 \
            &vbuf[bufi][(w * 16) * 64]);                                       \
    gload16(Vb + (size_t)row1 * SEQ + kvb + ((c16 ^ r8) << 3),                 \
            &vbuf[bufi][(w * 16 + 8) * 64]);                                   \
  } while (0)

  STAGE(0, t0);
  __syncthreads();

  int cur = 0;
  for (int t = t0; t < tend; ++t) {
    const int kv0 = t * 64;
    if (t + 1 < tend) STAGE(cur ^ 1, t + 1);

    const char* kb = (const char*)kbuf[cur];
    const char* vb = (const char*)vbuf[cur];

    short8 kf0[4], kf1[4];
#pragma unroll
    for (int cf = 0; cf < 4; cf++) {
      const int kr = (cf * 16 + cl) * 128;
      kf0[cf] = *(const short8*)(kb + kr + ((g ^ fsw) << 4));
      kf1[cf] = *(const short8*)(kb + kr + (((4 + g) ^ fsw) << 4));
    }

    f32x4 s4[4];
#pragma unroll
    for (int cf = 0; cf < 4; cf++) {
      f32x4 z; z[0] = z[1] = z[2] = z[3] = 0.f;
      z = mfma16(kf0[cf], qf0, z);
      s4[cf] = mfma16(kf1[cf], qf1, z);
    }

    if (t == bq) {
#pragma unroll
      for (int cf = 0; cf < 4; cf++) {
        const int kvb2 = kv0 + cf * 16 + g * 4;
#pragma unroll
        for (int r = 0; r < 4; r++)
          s4[cf][r] = (kvb2 + r <= q0 + cl) ? s4[cf][r] : -INFINITY;
      }
    }

    float tm[4];
#pragma unroll
    for (int cf = 0; cf < 4; cf++)
      tm[cf] = fmaxf(fmaxf(s4[cf][0], s4[cf][1]), fmaxf(s4[cf][2], s4[cf][3]));
    float mt = fmaxf(fmaxf(tm[0], tm[1]), fmaxf(tm[2], tm[3]));
    mt = xor16_max(mt);
    mt = xor32_max(mt);

    if (!__all(mt <= mrow + 8.0f)) {
      const float mn = fmaxf(mrow, mt);
      const float corr = __expf(mrow - mn);
      mrow = mn;
      lrow *= corr;
      float cb[4];
#pragma unroll
      for (int r = 0; r < 4; r++) cb[r] = __shfl(corr, g * 20 + r);
#pragma unroll
      for (int cf = 0; cf < 4; cf++) {
        o[cf][0] *= cb[0]; o[cf][1] *= cb[1];
        o[cf][2] *= cb[2]; o[cf][3] *= cb[3];
      }
    }

    float rs = 0.f;
#pragma unroll
    for (int cf = 0; cf < 4; cf++) {
      const float p0 = __expf(s4[cf][0] - mrow);
      const float p1 = __expf(s4[cf][1] - mrow);
      const float p2 = __expf(s4[cf][2] - mrow);
      const float p3 = __expf(s4[cf][3] - mrow);
      rs += (p0 + p1) + (p2 + p3);
      uint2 val;
      val.x = cvt_pk_bf16(p0, p1);
      val.y = cvt_pk_bf16(p2, p3);
      *(uint2*)(plds + prow + (((cf * 32) + (g * 8)) ^ swz)) = val;
    }
    rs = xor16_sum(rs);
    rs = xor32_sum(rs);
    lrow += rs;

    // Fence: P ds_writes above are uint2-typed, PV ds_reads below are
    // short8-typed -- TBAA says no-alias; keep the RAW pair ordered.
    asm volatile("" ::: "memory");

#pragma unroll
    for (int f = 0; f < 2; ++f) {
      const short8 pf = *(const short8*)(plds + prow + ((f * 64 + g * 16) ^ swz));
#pragma unroll
      for (int cf = 0; cf < 4; cf++) {
        const int vr = (cf * 16 + cl) * 128;
        const short8 vfa = *(const short8*)(vb + vr + (((f * 4 + g) ^ fsw) << 4));
        o[cf] = mfma16(pf, vfa, o[cf]);
      }
    }

    __syncthreads();
    cur ^= 1;
  }

  const int qg = bq * 4 + w;
  const int k2 = qg >> 6;
  const int slot = b * 640 + 32 * k2 * (k2 + 1) + (qg & 63) * (k2 + 1) + c;

  if (lane < 16) {
    ml[(size_t)slot * 32 + cl * 2 + 0] = mrow;
    ml[(size_t)slot * 32 + cl * 2 + 1] = lrow;
  }
#pragma unroll
  for (int cf = 0; cf < 4; cf++)
#pragma unroll
    for (int r = 0; r < 4; r++)
      opart[(size_t)slot * 1024 + (g * 4 + r) * 64 + cf * 16 + cl] = f2bf(o[cf][r]);
#undef STAGE
}

// ---------------- Kernel 3: combine partials (bf16 opart) -------------------
__global__ __launch_bounds__(256) void combine_kernel(const u16* __restrict__ opart,
                                                      const float* __restrict__ ml,
                                                      float* __restrict__ out) {
  const int tid = threadIdx.x;
  const int row = blockIdx.x * 16 + (tid >> 4);   // 0..16383
  const int d = (tid & 15) * 4;
  const int b = row >> 12;
  const int rowb = row & 4095;
  const int qg = rowb >> 4;
  const int r = rowb & 15;
  const int k2 = qg >> 6;
  const int nc = k2 + 1;
  const int sbase = b * 640 + 32 * k2 * (k2 + 1) + (qg & 63) * nc;

  float M = -INFINITY;
  float ms[4], ls[4];
  for (int cc = 0; cc < nc; cc++) {
    ms[cc] = ml[(size_t)(sbase + cc) * 32 + r * 2 + 0];
    ls[cc] = ml[(size_t)(sbase + cc) * 32 + r * 2 + 1];
    M = fmaxf(M, ms[cc]);
  }
  float L = 0.f;
  float4 acc = {0.f, 0.f, 0.f, 0.f};
  for (int cc = 0; cc < nc; cc++) {
    const float wgt = __expf(ms[cc] - M);
    L += ls[cc] * wgt;
    ushort4 ov = *(const ushort4*)(opart + (size_t)(sbase + cc) * 1024 + r * 64 + d);
    acc.x += bf2f(ov.x) * wgt; acc.y += bf2f(ov.y) * wgt;
    acc.z += bf2f(ov.z) * wgt; acc.w += bf2f(ov.w) * wgt;
  }
  const float inv = 1.0f / L;
  float4 res;
  res.x = rintf(acc.x * inv * 1.0e4f) * 1.0e-4f;
  res.y = rintf(acc.y * inv * 1.0e4f) * 1.0e-4f;
  res.z = rintf(acc.z * inv * 1.0e4f) * 1.0e-4f;
  res.w = rintf(acc.w * inv * 1.0e4f) * 1.0e-4f;
  *(float4*)(out + (size_t)row * AD + d) = res;
}

extern "C" void kernel_launch(void* const* d_in, const int* in_sizes, int n_in,
                              void* d_out, int out_size, void* d_ws, size_t ws_size,
                              hipStream_t stream) {
  const float* emb = (const float*)d_in[0];
  const float* Wq  = (const float*)d_in[1];
  const float* Wk  = (const float*)d_in[2];
  const float* Wv  = (const float*)d_in[3];
  float* out = (float*)d_out;

  char* ws = (char*)d_ws;
  u16* Wt = (u16*)ws;                               // 294912 B
  u16* Q  = (u16*)(ws + 294912);                    // 2 MiB each
  u16* K  = Q + (size_t)BS * AD;
  u16* Vt = K + (size_t)BS * AD;
  u16* opart = (u16*)(ws + 294912 + 3 * (size_t)BS * AD * 2);  // 2560*2KB bf16
  float* ml  = (float*)(ws + 294912 + 3 * (size_t)BS * AD * 2
                        + (size_t)2560 * 1024 * 2);            // 2560*128B

  wt_kernel<<<(3 * AD * EMB + 255) / 256, 256, 0, stream>>>(Wq, Wk, Wv, Wt);
  proj_kernel<<<BS / 32, 512, 0, stream>>>(emb, Wt, Q, K, Vt);
  flash_part<<<640, 256, 0, stream>>>(Q, K, Vt, opart, ml);
  combine_kernel<<<BS / 16, 256, 0, stream>>>(opart, ml, out);
}